// Round 16
// baseline (449.402 us; speedup 1.0000x reference)
//
#include <hip/hip_runtime.h>
#include <stdint.h>

// BConv2d via MFMA i8 implicit GEMM (R10 core + A-only 1-deep pipeline).
// out = conv2d(sign(x), sign(w), pad=1) + b ; N=32, Cin=256, H=W=56, Cout=256, K=3.
//
// sign as i8 {+1,-1}, zero padding as i8 0 (exact). conv = 9 tap-shifted
// GEMMs, K=256, i32 acc via v_mfma_i32_32x32x32_i8. C/D layout:
// col=lane&31, row=(reg&3)+8*(reg>>2)+4*(lane>>5) (verified R8-R15).
//
// TLP x ILP map: (16w,noILP)=85us R10; (16w,A+B-ILP)=spill R12/R13;
// (8w,*)=104-126 R14/R15 -> TLP dominates; only unexplored cell is
// 16w + SMALL ILP. R16 = R10 + A-only alternating prefetch (+12 regs,
// B stays single-set) + sched_barrier(0) between next-A loads and current
// MFMAs so the compiler cannot sink the prefetch (R6/R10 failure mode).
// A's L2 latency (~200-400cy) is the dominant exposed stall; one group
// (~220cy at 4 waves/SIMD) of lead time covers it.

#define NBATCH 32
#define CIN    256
#define COUT   256
#define HH     56
#define WW     56
#define HW     (HH*WW)          // 3136
#define NPIX   (NBATCH*HW)      // 100352

#define PW    58                // padded bit-image width/height
#define PROW  (PW*8)            // 464 words per padded row
#define PIMG  (PW*PW*8)         // 26912 words per padded image

#define XP_BYTES  ((size_t)NBATCH * PIMG * 4)  // 3,444,736 (16-aligned)
#define WQ_BYTES  ((size_t)9 * 8 * 256 * 32)   // 589,824

typedef int i32x4  __attribute__((ext_vector_type(4)));
typedef int i32x16 __attribute__((ext_vector_type(16)));

// ---- pack x bits: wave handles 64 channels (2 words) for 64 pixels
__global__ __launch_bounds__(256) void pack_x_kernel(
    const float* __restrict__ x, uint32_t* __restrict__ xp)
{
    int lane = threadIdx.x & 63;
    int wv   = threadIdx.x >> 6;               // 0..3 -> channel group
    int pix  = blockIdx.x * 64 + lane;         // 1568 blocks * 64 == NPIX
    int n  = pix / HW;
    int hw = pix - n * HW;
    int h  = hw / WW;
    int w_ = hw - h * WW;
    const float* xb = x + ((size_t)n * CIN + (size_t)wv * 64) * HW + hw;

    uint32_t w0 = 0, w1 = 0;
    #pragma unroll
    for (int j = 0; j < 32; ++j) {
        w0 |= (xb[(size_t)j * HW]        >= 0.0f ? 1u : 0u) << j;
        w1 |= (xb[(size_t)(j + 32) * HW] >= 0.0f ? 1u : 0u) << j;
    }
    uint32_t* dst = xp + (size_t)n * PIMG + (size_t)(h + 1) * PROW
                       + (size_t)(w_ + 1) * 8 + wv * 2;
    *(uint2*)dst = make_uint2(w0, w1);
}

// ---- pack w -> i8 {+1,-1}, layout wq[t][c8][co][slot], slot = ci&31
__global__ __launch_bounds__(256) void pack_w2_kernel(
    const float* __restrict__ w, int8_t* __restrict__ wq)
{
    int co = blockIdx.x, ci = threadIdx.x;
    const float* wb = w + ((size_t)co * CIN + ci) * 9;
    int c8 = ci >> 5, s = ci & 31;
    #pragma unroll
    for (int t = 0; t < 9; ++t) {
        wq[((size_t)(t * 8 + c8) * 256 + co) * 32 + s] =
            (wb[t] >= 0.0f) ? (int8_t)1 : (int8_t)-1;
    }
}

// ---- conv
#define LOADB(gi) { \
    const int dw_ = (gi) >> 3, c8_ = (gi) & 7; \
    const int col_ = l31 + cb * 32 + dw_; \
    const int sw_ = (col_ & 15) << 4; \
    const char* xc_ = xtb + (col_ << 8); \
    const int sx_ = ((c8_ << 5) + hi16) ^ sw_; \
    b0 = *(const i32x4*)(xc_ + ((0 * 66) << 8) + sx_); \
    b1 = *(const i32x4*)(xc_ + ((1 * 66) << 8) + sx_); \
    b2 = *(const i32x4*)(xc_ + ((2 * 66) << 8) + sx_); \
    b3 = *(const i32x4*)(xc_ + ((3 * 66) << 8) + sx_); }

#define LOADA(gi, A0, A1, A2) { \
    const int dw_ = (gi) >> 3, c8_ = (gi) & 7; \
    const char* wa_ = wql + (size_t)(dw_ * 8 + c8_) * 8192; \
    A0 = *(const i32x4*)(wa_); \
    A1 = *(const i32x4*)(wa_ + 196608); \
    A2 = *(const i32x4*)(wa_ + 393216); }

#define MFMA6(A0, A1, A2) \
    accA = __builtin_amdgcn_mfma_i32_32x32x32_i8(A0, b0, accA, 0, 0, 0); \
    accB = __builtin_amdgcn_mfma_i32_32x32x32_i8(A0, b1, accB, 0, 0, 0); \
    accA = __builtin_amdgcn_mfma_i32_32x32x32_i8(A1, b1, accA, 0, 0, 0); \
    accB = __builtin_amdgcn_mfma_i32_32x32x32_i8(A1, b2, accB, 0, 0, 0); \
    accA = __builtin_amdgcn_mfma_i32_32x32x32_i8(A2, b2, accA, 0, 0, 0); \
    accB = __builtin_amdgcn_mfma_i32_32x32x32_i8(A2, b3, accB, 0, 0, 0);

__global__ __launch_bounds__(512, 4) void bconv_kernel(
    const uint32_t* __restrict__ xp, const int8_t* __restrict__ wq,
    const float* __restrict__ bias, float* __restrict__ out)
{
    __shared__ __align__(16) int8_t xt[4][66][256];   // 67,584 B
    __shared__ float bsh[256];

    int bx = blockIdx.x;               // 0..895
    int n  = bx / 28;
    int hb = bx - n * 28;
    int h  = hb * 2;                   // output rows h, h+1
    int tid = threadIdx.x, lane = tid & 63, wv = tid >> 6;

    if (tid < 256) bsh[tid] = bias[tid];

    // expand packed sign bits -> i8 (+1/-1); borders & cols>=58 -> 0
    const uint32_t* xpb = xp + (size_t)n * PIMG;
    for (int e = tid; e < 4 * 66 * 64; e += 512) {   // 33 iters exactly
        int pr  = e / (66 * 64);
        int rem = e - pr * (66 * 64);
        int col = rem >> 6;
        int d   = rem & 63;            // output dword = 4 ci
        int prg = h + pr;              // padded global row
        bool val = (prg >= 1) & (prg <= 56) & (col >= 1) & (col <= 56);
        uint32_t wvv = 0;
        if (val) wvv = xpb[(size_t)prg * PROW + col * 8 + (d >> 3)];
        uint32_t nib = (wvv >> ((d & 7) * 4)) & 0xFu;
        uint32_t sp  = (nib * 0x00204081u) & 0x01010101u;   // bit k -> byte k
        uint32_t o   = val ? __builtin_amdgcn_perm(0u, 0x000001FFu, sp) : 0u;
        uint32_t ba  = (uint32_t)((((pr * 66 + col) << 8) | (d << 2))
                                  ^ ((col & 15) << 4));
        *(uint32_t*)((char*)&xt[0][0][0] + ba) = o;
    }
    __syncthreads();

    int l31  = lane & 31;
    int hi16 = (lane >> 5) << 4;
    const char* wql = (const char*)wq + (size_t)(wv * 32 + l31) * 32 + hi16;
    const char* xtb = (const char*)&xt[0][0][0];

    #pragma unroll 1
    for (int cb = 0; cb < 2; ++cb) {
        i32x16 accA = {0}, accB = {0};     // output rows h, h+1
        i32x4 a0, a1, a2;                  // A set 1 (even groups)
        i32x4 c0, c1, c2;                  // A set 2 (odd groups)
        i32x4 b0, b1, b2, b3;              // B (single set)

        LOADA(0, a0, a1, a2)
        #pragma unroll
        for (int gp = 0; gp < 12; ++gp) {
            // even group 2gp: B now, next A (odd) prefetched before MFMAs
            LOADB(2 * gp)
            LOADA(2 * gp + 1, c0, c1, c2)
            __builtin_amdgcn_sched_barrier(0);
            MFMA6(a0, a1, a2)
            // odd group 2gp+1: B now, next A (even) prefetched
            LOADB(2 * gp + 1)
            if (gp < 11) { LOADA(2 * gp + 2, a0, a1, a2) }
            __builtin_amdgcn_sched_barrier(0);
            MFMA6(c0, c1, c2)
        }

        // epilogue: C col=pixel(lane&31 within colblk), row=(r&3)+8*(r>>2)+4*(lane>>5)
        int pix = cb * 32 + l31;
        if (pix < WW) {
            float* op = out + (size_t)n * COUT * HW + (size_t)h * WW + pix;
            #pragma unroll
            for (int r = 0; r < 16; ++r) {
                int row = (r & 3) + 8 * (r >> 2) + ((lane >> 5) << 2);
                int co  = (wv << 5) + row;
                float bb = bsh[co];
                op[(size_t)co * HW]      = (float)accA[r] + bb;
                op[(size_t)co * HW + WW] = (float)accB[r] + bb;
            }
        }
    }
}

extern "C" void kernel_launch(void* const* d_in, const int* in_sizes, int n_in,
                              void* d_out, int out_size, void* d_ws, size_t ws_size,
                              hipStream_t stream) {
    const float* x = (const float*)d_in[0];
    const float* w = (const float*)d_in[1];
    const float* b = (const float*)d_in[2];
    float* out = (float*)d_out;

    uint32_t* xp = (uint32_t*)d_ws;
    int8_t*   wq = (int8_t*)((char*)d_ws + XP_BYTES);

    pack_x_kernel<<<NPIX / 64, 256, 0, stream>>>(x, xp);
    pack_w2_kernel<<<COUT, 256, 0, stream>>>(w, wq);

    bconv_kernel<<<NBATCH * (HH / 2), 512, 0, stream>>>(xp, wq, b, out);
}

// Round 17
// 100.045 us; speedup vs baseline: 4.4920x; 4.4920x over previous
//
#include <hip/hip_runtime.h>
#include <stdint.h>

// BConv2d via MFMA i8 implicit GEMM (R10 core, half-LDS blocks for 24 waves/CU).
// out = conv2d(sign(x), sign(w), pad=1) + b ; N=32, Cin=256, H=W=56, Cout=256, K=3.
//
// sign as i8 {+1,-1}, zero padding as i8 0 (exact). conv = 9 tap-shifted
// GEMMs, K=256, i32 acc via v_mfma_i32_32x32x32_i8. C/D layout:
// col=lane&31, row=(reg&3)+8*(reg>>2)+4*(lane>>5) (verified R8-R16).
//
// R12-R16 verdict: at 68.6KB LDS (2 blocks/CU, 16 waves) the compiler pins
// 64 arch regs and all source-level ILP spills or sinks; TLP is the proven
// lever (16w=85us, 8w=104-126us). R17: ONE colblk per block ->
// xt[4][34][256]=34.8KB -> LDS allows 4 blocks/CU; launch_bounds(512,6)
// (85-reg cap: 32 acc AGPR + ~50 arch = R10's arch budget) -> 24 waves/CU,
// 1.5x R10's TLP. K-loop body byte-identical to R10. cb2 innermost in grid
// for xp-halo L2 sharing.

#define NBATCH 32
#define CIN    256
#define COUT   256
#define HH     56
#define WW     56
#define HW     (HH*WW)          // 3136
#define NPIX   (NBATCH*HW)      // 100352

#define PW    58                // padded bit-image width/height
#define PROW  (PW*8)            // 464 words per padded row
#define PIMG  (PW*PW*8)         // 26912 words per padded image

#define XP_BYTES  ((size_t)NBATCH * PIMG * 4)  // 3,444,736 (16-aligned)
#define WQ_BYTES  ((size_t)9 * 8 * 256 * 32)   // 589,824

typedef int i32x4  __attribute__((ext_vector_type(4)));
typedef int i32x16 __attribute__((ext_vector_type(16)));

// ---- pack x bits: wave handles 64 channels (2 words) for 64 pixels
__global__ __launch_bounds__(256) void pack_x_kernel(
    const float* __restrict__ x, uint32_t* __restrict__ xp)
{
    int lane = threadIdx.x & 63;
    int wv   = threadIdx.x >> 6;               // 0..3 -> channel group
    int pix  = blockIdx.x * 64 + lane;         // 1568 blocks * 64 == NPIX
    int n  = pix / HW;
    int hw = pix - n * HW;
    int h  = hw / WW;
    int w_ = hw - h * WW;
    const float* xb = x + ((size_t)n * CIN + (size_t)wv * 64) * HW + hw;

    uint32_t w0 = 0, w1 = 0;
    #pragma unroll
    for (int j = 0; j < 32; ++j) {
        w0 |= (xb[(size_t)j * HW]        >= 0.0f ? 1u : 0u) << j;
        w1 |= (xb[(size_t)(j + 32) * HW] >= 0.0f ? 1u : 0u) << j;
    }
    uint32_t* dst = xp + (size_t)n * PIMG + (size_t)(h + 1) * PROW
                       + (size_t)(w_ + 1) * 8 + wv * 2;
    *(uint2*)dst = make_uint2(w0, w1);
}

// ---- pack w -> i8 {+1,-1}, layout wq[t][c8][co][slot], slot = ci&31
__global__ __launch_bounds__(256) void pack_w2_kernel(
    const float* __restrict__ w, int8_t* __restrict__ wq)
{
    int co = blockIdx.x, ci = threadIdx.x;
    const float* wb = w + ((size_t)co * CIN + ci) * 9;
    int c8 = ci >> 5, s = ci & 31;
    #pragma unroll
    for (int t = 0; t < 9; ++t) {
        wq[((size_t)(t * 8 + c8) * 256 + co) * 32 + s] =
            (wb[t] >= 0.0f) ? (int8_t)1 : (int8_t)-1;
    }
}

// ---- conv: block = (n, hpair, colblk); 8 waves = 8 co-groups
#define MFMA(ACC, A, B) \
    ACC = __builtin_amdgcn_mfma_i32_32x32x32_i8(A, B, ACC, 0, 0, 0);

__global__ __launch_bounds__(512, 6) void bconv_kernel(
    const uint32_t* __restrict__ xp, const int8_t* __restrict__ wq,
    const float* __restrict__ bias, float* __restrict__ out)
{
    __shared__ __align__(16) int8_t xt[4][34][256];   // 34,816 B
    __shared__ float bsh[256];

    int bx  = blockIdx.x;              // 0..1791
    int cb2 = bx & 1;                  // colblk innermost (L2 halo sharing)
    int t2  = bx >> 1;                 // 0..895
    int n   = t2 / 28;
    int hb  = t2 - n * 28;
    int h   = hb * 2;                  // output rows h, h+1
    int tid = threadIdx.x, lane = tid & 63, wv = tid >> 6;

    if (tid < 256) bsh[tid] = bias[tid];

    // expand packed sign bits -> i8 (+1/-1); borders -> 0
    const uint32_t* xpb = xp + (size_t)n * PIMG;
    for (int e = tid; e < 4 * 34 * 64; e += 512) {   // 17 iters exactly
        int pr  = e / (34 * 64);
        int rem = e - pr * (34 * 64);
        int col = rem >> 6;            // 0..33 (tile col)
        int d   = rem & 63;            // output dword = 4 ci
        int prg = h + pr;              // padded global row
        int gcol = cb2 * 32 + col;     // padded global col
        bool val = (prg >= 1) & (prg <= 56) & (gcol >= 1) & (gcol <= 56);
        uint32_t wvv = 0;
        if (val) wvv = xpb[(size_t)prg * PROW + gcol * 8 + (d >> 3)];
        uint32_t nib = (wvv >> ((d & 7) * 4)) & 0xFu;
        uint32_t sp  = (nib * 0x00204081u) & 0x01010101u;   // bit k -> byte k
        uint32_t o   = val ? __builtin_amdgcn_perm(0u, 0x000001FFu, sp) : 0u;
        uint32_t ba  = (uint32_t)((((pr * 34 + col) << 8) | (d << 2))
                                  ^ ((col & 15) << 4));
        *(uint32_t*)((char*)&xt[0][0][0] + ba) = o;
    }
    __syncthreads();

    int l31  = lane & 31;
    int hi16 = (lane >> 5) << 4;
    const char* wql = (const char*)wq + (size_t)(wv * 32 + l31) * 32 + hi16;
    const char* xtb = (const char*)&xt[0][0][0];

    i32x16 accA = {0}, accB = {0};     // output rows h, h+1

    #pragma unroll 1
    for (int dw = 0; dw < 3; ++dw) {
        int col0 = l31 + dw;           // tile col 0..33
        int sw   = (col0 & 15) << 4;
        const char* xc = xtb + (col0 << 8);
        #pragma unroll
        for (int c8 = 0; c8 < 8; ++c8) {
            int sx = ((c8 << 5) + hi16) ^ sw;
            i32x4 b0 = *(const i32x4*)(xc + ((0 * 34) << 8) + sx);
            i32x4 b1 = *(const i32x4*)(xc + ((1 * 34) << 8) + sx);
            i32x4 b2 = *(const i32x4*)(xc + ((2 * 34) << 8) + sx);
            i32x4 b3 = *(const i32x4*)(xc + ((3 * 34) << 8) + sx);
            const char* wa = wql + (size_t)(dw * 8 + c8) * 8192;
            i32x4 a0 = *(const i32x4*)(wa);
            i32x4 a1 = *(const i32x4*)(wa + 196608);
            i32x4 a2 = *(const i32x4*)(wa + 393216);
            MFMA(accA, a0, b0) MFMA(accB, a0, b1)
            MFMA(accA, a1, b1) MFMA(accB, a1, b2)
            MFMA(accA, a2, b2) MFMA(accB, a2, b3)
        }
    }

    // epilogue: C col=pixel(l31 within colblk), row=(r&3)+8*(r>>2)+4*(lane>>5)
    int pix = cb2 * 32 + l31;
    if (pix < WW) {
        float* op = out + (size_t)n * COUT * HW + (size_t)h * WW + pix;
        #pragma unroll
        for (int r = 0; r < 16; ++r) {
            int row = (r & 3) + 8 * (r >> 2) + ((lane >> 5) << 2);
            int co  = (wv << 5) + row;
            float bb = bsh[co];
            op[(size_t)co * HW]      = (float)accA[r] + bb;
            op[(size_t)co * HW + WW] = (float)accB[r] + bb;
        }
    }
}

extern "C" void kernel_launch(void* const* d_in, const int* in_sizes, int n_in,
                              void* d_out, int out_size, void* d_ws, size_t ws_size,
                              hipStream_t stream) {
    const float* x = (const float*)d_in[0];
    const float* w = (const float*)d_in[1];
    const float* b = (const float*)d_in[2];
    float* out = (float*)d_out;

    uint32_t* xp = (uint32_t*)d_ws;
    int8_t*   wq = (int8_t*)((char*)d_ws + XP_BYTES);

    pack_x_kernel<<<NPIX / 64, 256, 0, stream>>>(x, xp);
    pack_w2_kernel<<<COUT, 256, 0, stream>>>(w, wq);

    bconv_kernel<<<NBATCH * 28 * 2, 512, 0, stream>>>(xp, wq, b, out);
}